// Round 3
// baseline (337.302 us; speedup 1.0000x reference)
//
#include <hip/hip_runtime.h>
#include <hip/hip_bf16.h>

// B=256, S=512, H=1024, L=30
// out = [tanh(x0)|tanh(mean_sub)|tanh(mean_obj)] @ Wfold + btot
//   P1 = W_d2@W_out; Wd1o = W_d1@P1; Wfold[z] = W_z@Wd1o[z]
//   btot = b_out + b_d2@W_out + b_d1@P1 + [b_cls|b_e1|b_e2]@Wd1o

#define B_ 256
#define S_ 512
#define H_ 1024
#define L_ 30
#define NCHUNK 8   // 512/64 span rows per chunk
#define KC 32      // k-chunk per fold block
#define KS 32      // k-split (1024/KC)

// ---------------------------------------------------------------------------
// Span partial sums: grid (B, NCHUNK, 2), block 256 (float4/lane = full row).
// ---------------------------------------------------------------------------
__global__ __launch_bounds__(256) void span_partial_kernel(
    const float* __restrict__ x, const int* __restrict__ eidx,
    float* __restrict__ Pspan) {
  const int b = blockIdx.x;
  const int chunk = blockIdx.y;
  const int role = blockIdx.z;
  const int lo = eidx[b * 4 + 2 * role];
  const int hi = eidx[b * 4 + 2 * role + 1];
  int s0 = max(lo, chunk * 64);
  int s1 = min(hi, chunk * 64 + 64);
  if (s0 >= s1) return;

  const int col = threadIdx.x * 4;
  const float* base = x + (size_t)b * S_ * H_ + col;
  float ax0 = 0.f, ay0 = 0.f, az0 = 0.f, aw0 = 0.f;
  float ax1 = 0.f, ay1 = 0.f, az1 = 0.f, aw1 = 0.f;
  int s = s0;
  for (; s + 2 <= s1; s += 2) {
    float4 v0 = *(const float4*)(base + (size_t)s * H_);
    float4 v1 = *(const float4*)(base + (size_t)(s + 1) * H_);
    ax0 += v0.x; ay0 += v0.y; az0 += v0.z; aw0 += v0.w;
    ax1 += v1.x; ay1 += v1.y; az1 += v1.z; aw1 += v1.w;
  }
  if (s < s1) {
    float4 v0 = *(const float4*)(base + (size_t)s * H_);
    ax0 += v0.x; ay0 += v0.y; az0 += v0.z; aw0 += v0.w;
  }
  float4 o;
  o.x = ax0 + ax1; o.y = ay0 + ay1; o.z = az0 + az1; o.w = aw0 + aw1;
  *(float4*)(Pspan + (((size_t)b * 2 + role) * NCHUNK + chunk) * H_ + col) = o;
}

// ---------------------------------------------------------------------------
// fold32: C-partial[ks][Mtot][30] = A[128 rows, 32 k] @ S[32 k][30]
// block = 64 threads (1 wave), 2 rows/lane, acc in VGPRs.
// A staged in LDS [128][36] (b128-aligned, bank-shifted rows).
// S staged TRANSPOSED in LDS [30][36] -> inner loop reads St[n][kk..kk+3] as
// lane-uniform ds_read_b128 broadcasts (conflict-free), 30 reads per 240 FMA.
// z-select for the tri launch: z = bx >> zshift (zshift=30 disables).
// ---------------------------------------------------------------------------
__global__ __launch_bounds__(64) void fold32_kernel(
    const float* __restrict__ A0, const float* __restrict__ A1,
    const float* __restrict__ A2, const float* __restrict__ Smat,
    long s_z_stride, float* __restrict__ Cp, int Mtot, int zshift) {
  __shared__ float As[128][36];
  __shared__ float St[30][36];
  const int t = threadIdx.x;
  const int bx = blockIdx.x;
  const int ks = blockIdx.y;
  const int k0 = ks * KC;
  const int z = bx >> zshift;
  const int arowbase = (bx - (z << zshift)) * 128;
  const int crowbase = bx * 128;
  const float* A = (z == 0) ? A0 : ((z == 1) ? A1 : A2);
  const float* S = Smat + (size_t)z * s_z_stride;

  // stage A: 128 rows x 32 k, coalesced float4
#pragma unroll
  for (int i = 0; i < 16; ++i) {
    int idx = t + i * 64;
    int r = idx >> 3;
    int c4 = (idx & 7) << 2;
    float4 v = *(const float4*)(A + (size_t)(arowbase + r) * H_ + k0 + c4);
    *(float4*)&As[r][c4] = v;
  }
  // stage S transposed: read S[k0+k][n] coalesced, write St[n][k]
#pragma unroll
  for (int i = 0; i < 15; ++i) {
    int idx = t + i * 64;  // < 960
    int k = idx / 30, n = idx - k * 30;
    St[n][k] = S[(size_t)(k0 + k) * L_ + n];
  }
  __syncthreads();

  float acc0[30], acc1[30];
#pragma unroll
  for (int n = 0; n < 30; ++n) { acc0[n] = 0.f; acc1[n] = 0.f; }

#pragma unroll
  for (int kk = 0; kk < KC; kk += 4) {
    float4 a0 = *(const float4*)&As[t][kk];
    float4 a1 = *(const float4*)&As[t + 64][kk];
#pragma unroll
    for (int n = 0; n < 30; ++n) {
      float4 s4 = *(const float4*)&St[n][kk];
      acc0[n] += a0.x * s4.x + a0.y * s4.y + a0.z * s4.z + a0.w * s4.w;
      acc1[n] += a1.x * s4.x + a1.y * s4.y + a1.z * s4.z + a1.w * s4.w;
    }
  }

  float* c0 = Cp + ((size_t)ks * Mtot + crowbase + t) * L_;
  float* c1 = Cp + ((size_t)ks * Mtot + crowbase + t + 64) * L_;
#pragma unroll
  for (int n = 0; n < 30; ++n) { c0[n] = acc0[n]; c1[n] = acc1[n]; }
}

// ---------------------------------------------------------------------------
// reduce32 (+ optional fused bias blocks): dst[i] = sum_p src[p*N+i]
// grid = nred blocks (+30 bias blocks when do_bias). block 256.
// ---------------------------------------------------------------------------
__global__ __launch_bounds__(256) void reduce32_kernel(
    const float* __restrict__ src, float* __restrict__ dst, int N, int nred,
    int do_bias,
    const float* __restrict__ b_out, const float* __restrict__ b_d2,
    const float* __restrict__ W_out, const float* __restrict__ b_d1,
    const float* __restrict__ P1, const float* __restrict__ b_cls,
    const float* __restrict__ b_e1, const float* __restrict__ b_e2,
    const float* __restrict__ Wd1o, float* __restrict__ btot) {
  const int t = threadIdx.x;
  if ((int)blockIdx.x < nred) {
    int i = blockIdx.x * 256 + t;
    if (i >= N) return;
    float s = 0.f;
#pragma unroll 8
    for (int p = 0; p < KS; ++p) s += src[(size_t)p * N + i];
    dst[i] = s;
    return;
  }
  if (!do_bias) return;
  // bias block: n = blockIdx.x - nred
  const int n = blockIdx.x - nred;
  __shared__ float red[256];
  float s = 0.f;
  for (int k = t; k < H_; k += 256) {
    s += b_d2[k] * W_out[(size_t)k * L_ + n];
    s += b_d1[k] * P1[(size_t)k * L_ + n];
    s += b_cls[k] * Wd1o[(size_t)k * L_ + n];
    s += b_e1[k] * Wd1o[(size_t)(H_ + k) * L_ + n];
    s += b_e2[k] * Wd1o[(size_t)(2 * H_ + k) * L_ + n];
  }
  red[t] = s;
  __syncthreads();
  for (int off = 128; off > 0; off >>= 1) {
    if (t < off) red[t] += red[t + off];
    __syncthreads();
  }
  if (t == 0) btot[n] = red[0] + b_out[n];
}

// ---------------------------------------------------------------------------
// Final: build T[b] in LDS (tanh(x0), tanh(span means from partials)), then
// out[b][n] = T[b] . Wfold[:,n] + btot[n].  grid B, block 256.
// ---------------------------------------------------------------------------
__global__ __launch_bounds__(256) void final_kernel(
    const float* __restrict__ x, const int* __restrict__ eidx,
    const float* __restrict__ Pspan, const float* __restrict__ Wf,
    const float* __restrict__ btot, float* __restrict__ out) {
  __shared__ float Ts[3 * H_];
  __shared__ float red[8][30];
  const int b = blockIdx.x;
  const int t = threadIdx.x;
  const int col = t * 4;

  {
    float4 v = *(const float4*)(x + (size_t)b * S_ * H_ + col);
    Ts[col + 0] = tanhf(v.x);
    Ts[col + 1] = tanhf(v.y);
    Ts[col + 2] = tanhf(v.z);
    Ts[col + 3] = tanhf(v.w);
  }
#pragma unroll
  for (int role = 0; role < 2; ++role) {
    const int lo = eidx[b * 4 + 2 * role];
    const int hi = eidx[b * 4 + 2 * role + 1];
    const int c0 = lo >> 6;
    const int c1 = (hi - 1) >> 6;
    float ax = 0.f, ay = 0.f, az = 0.f, aw = 0.f;
    for (int c = c0; c <= c1; ++c) {
      float4 v = *(const float4*)(Pspan + (((size_t)b * 2 + role) * NCHUNK + c) * H_ + col);
      ax += v.x; ay += v.y; az += v.z; aw += v.w;
    }
    const float inv = 1.0f / (float)(hi - lo);
    float* Td = Ts + (1 + role) * H_ + col;
    Td[0] = tanhf(ax * inv);
    Td[1] = tanhf(ay * inv);
    Td[2] = tanhf(az * inv);
    Td[3] = tanhf(aw * inv);
  }
  __syncthreads();

  if (t < 240) {
    const int n = t % 30, p = t / 30;
    const int k0 = p * 384;
    float s = 0.f;
#pragma unroll 4
    for (int k = k0; k < k0 + 384; ++k) s += Ts[k] * Wf[(size_t)k * L_ + n];
    red[p][n] = s;
  }
  __syncthreads();
  if (t < L_) {
    float s = btot[t];
#pragma unroll
    for (int p = 0; p < 8; ++p) s += red[p][t];
    out[(size_t)b * L_ + t] = s;
  }
}

extern "C" void kernel_launch(void* const* d_in, const int* in_sizes, int n_in,
                              void* d_out, int out_size, void* d_ws, size_t ws_size,
                              hipStream_t stream) {
  const float* x = (const float*)d_in[0];
  const int* eidx = (const int*)d_in[1];
  const float* W_cls = (const float*)d_in[2];
  const float* b_cls = (const float*)d_in[3];
  const float* W_e1 = (const float*)d_in[4];
  const float* b_e1 = (const float*)d_in[5];
  const float* W_e2 = (const float*)d_in[6];
  const float* b_e2 = (const float*)d_in[7];
  const float* W_d1 = (const float*)d_in[8];
  const float* b_d1 = (const float*)d_in[9];
  const float* W_d2 = (const float*)d_in[10];
  const float* b_d2 = (const float*)d_in[11];
  const float* W_out = (const float*)d_in[12];
  const float* b_out = (const float*)d_in[13];
  float* out = (float*)d_out;

  float* ws = (float*)d_ws;
  float* Pspan = ws;                   // 256*2*8*1024 = 4,194,304
  float* P1p   = Pspan + 4194304;      // 32*1024*30  =   983,040
  float* P1    = P1p + 983040;         // 1024*30     =    30,720
  float* Wp    = P1 + 30720;           // 32*3072*30  = 2,949,120
  float* Wd1o  = Wp + 2949120;         // 3072*30     =    92,160
  float* Wp2   = Wd1o + 92160;         // 32*3072*30  = 2,949,120
  float* Wfold = Wp2 + 2949120;        // 3072*30     =    92,160
  float* btot  = Wfold + 92160;        // 32
  // total ~11.3M floats ~45 MB

  // Big HBM read first.
  span_partial_kernel<<<dim3(B_, NCHUNK, 2), 256, 0, stream>>>(x, eidx, Pspan);

  // P1 = W_d2 @ W_out   (1024x30), 8x32 = 256 blocks
  fold32_kernel<<<dim3(H_ / 128, KS), 64, 0, stream>>>(
      W_d2, W_d2, W_d2, W_out, 0, P1p, H_, 30);
  reduce32_kernel<<<120, 256, 0, stream>>>(P1p, P1, H_ * L_, 120, 0,
      nullptr, nullptr, nullptr, nullptr, nullptr, nullptr, nullptr, nullptr,
      nullptr, nullptr);

  // Wd1o = W_d1 @ P1   (3072x30), 24x32 = 768 blocks
  fold32_kernel<<<dim3(3 * H_ / 128, KS), 64, 0, stream>>>(
      W_d1, W_d1, W_d1, P1, 0, Wp, 3 * H_, 30);
  reduce32_kernel<<<360, 256, 0, stream>>>(Wp, Wd1o, 3 * H_ * L_, 360, 0,
      nullptr, nullptr, nullptr, nullptr, nullptr, nullptr, nullptr, nullptr,
      nullptr, nullptr);

  // Wfold[z] = W_z @ Wd1o[z]  (3 x 1024x30), 24x32 = 768 blocks (z = bx>>3)
  fold32_kernel<<<dim3(3 * H_ / 128, KS), 64, 0, stream>>>(
      W_cls, W_e1, W_e2, Wd1o, (long)H_ * L_, Wp2, 3 * H_, 3);
  // reduce Wfold + fused bias (30 extra blocks)
  reduce32_kernel<<<390, 256, 0, stream>>>(Wp2, Wfold, 3 * H_ * L_, 360, 1,
      b_out, b_d2, W_out, b_d1, P1, b_cls, b_e1, b_e2, Wd1o, btot);

  final_kernel<<<B_, 256, 0, stream>>>(x, eidx, Pspan, Wfold, btot, out);
}

// Round 4
// 333.540 us; speedup vs baseline: 1.0113x; 1.0113x over previous
//
#include <hip/hip_runtime.h>
#include <hip/hip_bf16.h>

// B=256, S=512, H=1024, L=30
// out = [tanh(x0)|tanh(mean_sub)|tanh(mean_obj)] @ Wfold + btot
//   P1 = W_d2@W_out; Wd1o = W_d1@P1; Wfold[z] = W_z@Wd1o[z]
//   btot = b_out + b_d2@W_out + b_d1@P1 + [b_cls|b_e1|b_e2]@Wd1o
// Fold GEMMs: one thread per output element (M*30 outputs, K=1024 dot).
// No partials, no reduce kernels. 5 launches total.

#define B_ 256
#define S_ 512
#define H_ 1024
#define L_ 30
#define NCHUNK 8   // 512/64 span rows per chunk

// ---------------------------------------------------------------------------
// Span partial sums: grid (B, NCHUNK, 2), block 256 (float4/lane = full row).
// Block sums rows [chunk*64, chunk*64+64) ∩ [lo,hi) -> Pspan[b][role][chunk][H].
// ---------------------------------------------------------------------------
__global__ __launch_bounds__(256) void span_partial_kernel(
    const float* __restrict__ x, const int* __restrict__ eidx,
    float* __restrict__ Pspan) {
  const int b = blockIdx.x;
  const int chunk = blockIdx.y;
  const int role = blockIdx.z;
  const int lo = eidx[b * 4 + 2 * role];
  const int hi = eidx[b * 4 + 2 * role + 1];
  int s0 = max(lo, chunk * 64);
  int s1 = min(hi, chunk * 64 + 64);
  if (s0 >= s1) return;

  const int col = threadIdx.x * 4;
  const float* base = x + (size_t)b * S_ * H_ + col;
  float ax0 = 0.f, ay0 = 0.f, az0 = 0.f, aw0 = 0.f;
  float ax1 = 0.f, ay1 = 0.f, az1 = 0.f, aw1 = 0.f;
  int s = s0;
  for (; s + 2 <= s1; s += 2) {
    float4 v0 = *(const float4*)(base + (size_t)s * H_);
    float4 v1 = *(const float4*)(base + (size_t)(s + 1) * H_);
    ax0 += v0.x; ay0 += v0.y; az0 += v0.z; aw0 += v0.w;
    ax1 += v1.x; ay1 += v1.y; az1 += v1.z; aw1 += v1.w;
  }
  if (s < s1) {
    float4 v0 = *(const float4*)(base + (size_t)s * H_);
    ax0 += v0.x; ay0 += v0.y; az0 += v0.z; aw0 += v0.w;
  }
  float4 o;
  o.x = ax0 + ax1; o.y = ay0 + ay1; o.z = az0 + az1; o.w = aw0 + aw1;
  *(float4*)(Pspan + (((size_t)b * 2 + role) * NCHUNK + chunk) * H_ + col) = o;
}

// ---------------------------------------------------------------------------
// Generic fold step: C[m][n] = sum_k A[m][k] * S[k][n], one thread per (m,n).
// Lanes with equal m broadcast A row (L1, linear k walk); S reads are 120 B
// coalesced groups, L2-resident.
// ---------------------------------------------------------------------------
__global__ __launch_bounds__(256) void fold_rows_kernel(
    const float* __restrict__ A, const float* __restrict__ S,
    float* __restrict__ C, int Mtot) {
  int idx = blockIdx.x * 256 + threadIdx.x;
  if (idx >= Mtot * L_) return;
  int m = idx / L_, n = idx - m * L_;
  const float* a = A + (size_t)m * H_;
  const float* s = S + n;
  float acc = 0.f;
#pragma unroll 8
  for (int k = 0; k < H_; ++k) acc += a[k] * s[(size_t)k * L_];
  C[idx] = acc;
}

// ---------------------------------------------------------------------------
// Last fold step (z-selected A) + 3 bias rows:
//   Wfold[z*H+r][n] = sum_k W_z[r][k] * Wd1o[z*H+k][n]
//   rbias[0][n] = [b_cls|b_e1|b_e2] @ Wd1o   (3072-k)
//   rbias[1][n] = b_d1 @ P1                  (1024-k)
//   rbias[2][n] = b_d2 @ W_out               (1024-k)
// ---------------------------------------------------------------------------
__global__ __launch_bounds__(256) void foldC_kernel(
    const float* __restrict__ Wcls, const float* __restrict__ We1,
    const float* __restrict__ We2, const float* __restrict__ Wd1o,
    const float* __restrict__ Wout, const float* __restrict__ P1,
    const float* __restrict__ b_cls, const float* __restrict__ b_e1,
    const float* __restrict__ b_e2, const float* __restrict__ b_d1,
    const float* __restrict__ b_d2,
    float* __restrict__ Wfold, float* __restrict__ rbias) {
  int idx = blockIdx.x * 256 + threadIdx.x;
  if (idx < 3 * H_ * L_) {
    int m = idx / L_, n = idx - m * L_;
    int z = m >> 10, r = m & (H_ - 1);
    const float* A = (z == 0) ? Wcls : (z == 1) ? We1 : We2;
    const float* a = A + (size_t)r * H_;
    const float* s = Wd1o + (size_t)z * H_ * L_ + n;
    float acc = 0.f;
#pragma unroll 8
    for (int k = 0; k < H_; ++k) acc += a[k] * s[(size_t)k * L_];
    Wfold[idx] = acc;
    return;
  }
  int extra = idx - 3 * H_ * L_;
  if (extra >= 3 * L_) return;
  int r = extra / L_, n = extra - r * L_;
  float acc = 0.f;
  if (r == 0) {
    for (int k = 0; k < H_; ++k) {
      acc += b_cls[k] * Wd1o[(size_t)k * L_ + n]
           + b_e1[k] * Wd1o[(size_t)(H_ + k) * L_ + n]
           + b_e2[k] * Wd1o[(size_t)(2 * H_ + k) * L_ + n];
    }
  } else if (r == 1) {
    for (int k = 0; k < H_; ++k) acc += b_d1[k] * P1[(size_t)k * L_ + n];
  } else {
    for (int k = 0; k < H_; ++k) acc += b_d2[k] * Wout[(size_t)k * L_ + n];
  }
  rbias[extra] = acc;
}

// ---------------------------------------------------------------------------
// Final: build T[b] in LDS (tanh(x0), tanh(span means from partials)), then
// out[b][n] = T[b] . Wfold[:,n] + btot[n].  grid B, block 256.
// btot assembled inline: b_out + rbias rows.
// ---------------------------------------------------------------------------
__global__ __launch_bounds__(256) void final_kernel(
    const float* __restrict__ x, const int* __restrict__ eidx,
    const float* __restrict__ Pspan, const float* __restrict__ Wf,
    const float* __restrict__ b_out, const float* __restrict__ rbias,
    float* __restrict__ out) {
  __shared__ float Ts[3 * H_];
  __shared__ float red[8][30];
  const int b = blockIdx.x;
  const int t = threadIdx.x;
  const int col = t * 4;

  {
    float4 v = *(const float4*)(x + (size_t)b * S_ * H_ + col);
    Ts[col + 0] = tanhf(v.x);
    Ts[col + 1] = tanhf(v.y);
    Ts[col + 2] = tanhf(v.z);
    Ts[col + 3] = tanhf(v.w);
  }
#pragma unroll
  for (int role = 0; role < 2; ++role) {
    const int lo = eidx[b * 4 + 2 * role];
    const int hi = eidx[b * 4 + 2 * role + 1];
    const int c0 = lo >> 6;
    const int c1 = (hi - 1) >> 6;
    float ax = 0.f, ay = 0.f, az = 0.f, aw = 0.f;
    for (int c = c0; c <= c1; ++c) {
      float4 v = *(const float4*)(Pspan + (((size_t)b * 2 + role) * NCHUNK + c) * H_ + col);
      ax += v.x; ay += v.y; az += v.z; aw += v.w;
    }
    const float inv = 1.0f / (float)(hi - lo);
    float* Td = Ts + (1 + role) * H_ + col;
    Td[0] = tanhf(ax * inv);
    Td[1] = tanhf(ay * inv);
    Td[2] = tanhf(az * inv);
    Td[3] = tanhf(aw * inv);
  }
  __syncthreads();

  if (t < 240) {
    const int n = t % 30, p = t / 30;
    const int k0 = p * 384;
    float s = 0.f;
#pragma unroll 4
    for (int k = k0; k < k0 + 384; ++k) s += Ts[k] * Wf[(size_t)k * L_ + n];
    red[p][n] = s;
  }
  __syncthreads();
  if (t < L_) {
    float s = b_out[t] + rbias[t] + rbias[L_ + t] + rbias[2 * L_ + t];
#pragma unroll
    for (int p = 0; p < 8; ++p) s += red[p][t];
    out[(size_t)b * L_ + t] = s;
  }
}

extern "C" void kernel_launch(void* const* d_in, const int* in_sizes, int n_in,
                              void* d_out, int out_size, void* d_ws, size_t ws_size,
                              hipStream_t stream) {
  const float* x = (const float*)d_in[0];
  const int* eidx = (const int*)d_in[1];
  const float* W_cls = (const float*)d_in[2];
  const float* b_cls = (const float*)d_in[3];
  const float* W_e1 = (const float*)d_in[4];
  const float* b_e1 = (const float*)d_in[5];
  const float* W_e2 = (const float*)d_in[6];
  const float* b_e2 = (const float*)d_in[7];
  const float* W_d1 = (const float*)d_in[8];
  const float* b_d1 = (const float*)d_in[9];
  const float* W_d2 = (const float*)d_in[10];
  const float* b_d2 = (const float*)d_in[11];
  const float* W_out = (const float*)d_in[12];
  const float* b_out = (const float*)d_in[13];
  float* out = (float*)d_out;

  float* ws = (float*)d_ws;
  float* Pspan = ws;                   // 256*2*8*1024 = 4,194,304
  float* P1    = Pspan + 4194304;      // 1024*30     =    30,720
  float* Wd1o  = P1 + 30720;           // 3072*30     =    92,160
  float* Wfold = Wd1o + 92160;         // 3072*30     =    92,160
  float* rbias = Wfold + 92160;        // 96
  // total ~4.41M floats ~17.6 MB

  // Big HBM read first.
  span_partial_kernel<<<dim3(B_, NCHUNK, 2), 256, 0, stream>>>(x, eidx, Pspan);

  // P1 = W_d2 @ W_out   (1024x30 outputs -> 120 blocks)
  fold_rows_kernel<<<(H_ * L_ + 255) / 256, 256, 0, stream>>>(W_d2, W_out, P1, H_);

  // Wd1o = W_d1 @ P1    (3072x30 outputs -> 360 blocks)
  fold_rows_kernel<<<(3 * H_ * L_ + 255) / 256, 256, 0, stream>>>(W_d1, P1, Wd1o, 3 * H_);

  // Wfold[z] = W_z @ Wd1o[z] + bias rows (92250 outputs -> 361 blocks)
  foldC_kernel<<<(3 * H_ * L_ + 3 * L_ + 255) / 256, 256, 0, stream>>>(
      W_cls, W_e1, W_e2, Wd1o, W_out, P1,
      b_cls, b_e1, b_e2, b_d1, b_d2, Wfold, rbias);

  final_kernel<<<B_, 256, 0, stream>>>(x, eidx, Pspan, Wfold, b_out, rbias, out);
}

// Round 5
// 237.805 us; speedup vs baseline: 1.4184x; 1.4026x over previous
//
#include <hip/hip_runtime.h>
#include <hip/hip_bf16.h>

// B=256, S=512, H=1024, L=30
// out = [tanh(x0)|tanh(mean_sub)|tanh(mean_obj)] @ Wfold + btot
//   P1 = W_d2@W_out; Wd1o = W_d1@P1; Wfold[z] = W_z@Wd1o[z]
//   btot = b_out + b_d2@W_out + b_d1@P1 + [b_cls|b_e1|b_e2]@Wd1o
// Fold GEMMs: ONE WAVE PER OUTPUT ROW, K=1024 split across 64 lanes (16 each),
// 30 VGPR accumulators, shfl_xor tree reduce. High TLP, streaming loads.
// 4 launches: [span+fold1], fold2, fold3+bias, final.

#define B_ 256
#define S_ 512
#define H_ 1024
#define L_ 30
#define LP 32       // padded column stride for intermediates
#define CH 32       // span chunk rows
#define NCHUNK 16   // 512/CH

// ---------------------------------------------------------------------------
// One wave computes crow[0..29] = arow[0..1023] . S[:, n] (S row-major,
// row stride SSTRIDE). Lane l owns k in [16l, 16l+16).
// ---------------------------------------------------------------------------
template <int SSTRIDE>
__device__ __forceinline__ void fold_row(
    const float* __restrict__ arow, const float* __restrict__ S,
    float* __restrict__ crow) {
  const int lane = threadIdx.x & 63;
  const float* a = arow + lane * 16;
  const float* s = S + (size_t)(lane * 16) * SSTRIDE;
  float acc[30];
#pragma unroll
  for (int n = 0; n < 30; ++n) acc[n] = 0.f;
#pragma unroll
  for (int j = 0; j < 16; ++j) {
    const float av = a[j];
    const float* sj = s + j * SSTRIDE;
#pragma unroll
    for (int n = 0; n < 30; ++n) acc[n] += av * sj[n];
  }
#pragma unroll
  for (int n = 0; n < 30; ++n) {
#pragma unroll
    for (int m = 1; m < 64; m <<= 1) acc[n] += __shfl_xor(acc[n], m);
  }
  if (lane == 0) {
#pragma unroll
    for (int n = 0; n < 30; ++n) crow[n] = acc[n];
  }
}

// ---------------------------------------------------------------------------
// Span partials (grid 256 x 17 x 2, block 256) + fold1 hung on chunk==16:
//   chunk<16: sum rows [chunk*32, +32) ∩ [lo,hi) of x[b,:,:] -> Pspan
//   chunk==16, role==0: wave w of block b computes P1 row b*4+w = W_d2 . W_out
// ---------------------------------------------------------------------------
__global__ __launch_bounds__(256) void span_fold1_kernel(
    const float* __restrict__ x, const int* __restrict__ eidx,
    const float* __restrict__ W_d2, const float* __restrict__ W_out,
    float* __restrict__ Pspan, float* __restrict__ P1p) {
  const int b = blockIdx.x;
  const int chunk = blockIdx.y;
  const int role = blockIdx.z;

  if (chunk == NCHUNK) {
    if (role == 0) {
      const int row = b * 4 + (threadIdx.x >> 6);  // 0..1023
      fold_row<30>(W_d2 + (size_t)row * H_, W_out, P1p + (size_t)row * LP);
    }
    return;
  }

  const int lo = eidx[b * 4 + 2 * role];
  const int hi = eidx[b * 4 + 2 * role + 1];
  int s0 = max(lo, chunk * CH);
  int s1 = min(hi, chunk * CH + CH);
  if (s0 >= s1) return;

  const int col = threadIdx.x * 4;
  const float* base = x + (size_t)b * S_ * H_ + col;
  float x0 = 0.f, y0 = 0.f, z0 = 0.f, w0 = 0.f;
  float x1 = 0.f, y1 = 0.f, z1 = 0.f, w1 = 0.f;
  float x2 = 0.f, y2 = 0.f, z2 = 0.f, w2 = 0.f;
  float x3 = 0.f, y3 = 0.f, z3 = 0.f, w3 = 0.f;
  int s = s0;
  for (; s + 4 <= s1; s += 4) {
    float4 v0 = *(const float4*)(base + (size_t)s * H_);
    float4 v1 = *(const float4*)(base + (size_t)(s + 1) * H_);
    float4 v2 = *(const float4*)(base + (size_t)(s + 2) * H_);
    float4 v3 = *(const float4*)(base + (size_t)(s + 3) * H_);
    x0 += v0.x; y0 += v0.y; z0 += v0.z; w0 += v0.w;
    x1 += v1.x; y1 += v1.y; z1 += v1.z; w1 += v1.w;
    x2 += v2.x; y2 += v2.y; z2 += v2.z; w2 += v2.w;
    x3 += v3.x; y3 += v3.y; z3 += v3.z; w3 += v3.w;
  }
  for (; s < s1; ++s) {
    float4 v = *(const float4*)(base + (size_t)s * H_);
    x0 += v.x; y0 += v.y; z0 += v.z; w0 += v.w;
  }
  float4 o;
  o.x = x0 + x1 + x2 + x3;
  o.y = y0 + y1 + y2 + y3;
  o.z = z0 + z1 + z2 + z3;
  o.w = w0 + w1 + w2 + w3;
  *(float4*)(Pspan + (((size_t)b * 2 + role) * NCHUNK + chunk) * H_ + col) = o;
}

// ---------------------------------------------------------------------------
// fold2: Wd1o32[row] = W_d1[row] . P1p   (3072 rows, 768 blocks x 4 waves)
// ---------------------------------------------------------------------------
__global__ __launch_bounds__(256) void fold2_kernel(
    const float* __restrict__ W_d1, const float* __restrict__ P1p,
    float* __restrict__ Wd1o32) {
  const int row = blockIdx.x * 4 + (threadIdx.x >> 6);  // 0..3071
  fold_row<LP>(W_d1 + (size_t)row * H_, P1p, Wd1o32 + (size_t)row * LP);
}

// ---------------------------------------------------------------------------
// fold3: Wfold32[z*H+r] = W_z[r] . Wd1o32[z-slice]  (768 blocks) + bias block.
// ---------------------------------------------------------------------------
__global__ __launch_bounds__(256) void fold3_kernel(
    const float* __restrict__ Wcls, const float* __restrict__ We1,
    const float* __restrict__ We2, const float* __restrict__ Wd1o32,
    const float* __restrict__ P1p, const float* __restrict__ W_out,
    const float* __restrict__ b_cls, const float* __restrict__ b_e1,
    const float* __restrict__ b_e2, const float* __restrict__ b_d1,
    const float* __restrict__ b_d2,
    float* __restrict__ Wfold32, float* __restrict__ rbias) {
  const int wid = threadIdx.x >> 6;
  const int lane = threadIdx.x & 63;

  if (blockIdx.x < 768) {
    const int row = blockIdx.x * 4 + wid;       // 0..3071
    const int z = row >> 10, r = row & (H_ - 1);
    const float* A = (z == 0) ? Wcls : (z == 1) ? We1 : We2;
    fold_row<LP>(A + (size_t)r * H_, Wd1o32 + (size_t)z * H_ * LP,
                 Wfold32 + (size_t)row * LP);
    return;
  }

  // bias block: wave0 -> [b_cls|b_e1|b_e2].Wd1o32 (K=3072)
  //             wave1 -> b_d1.P1p (K=1024), wave2 -> b_d2.W_out (K=1024)
  if (wid == 0) {
    float acc[30];
#pragma unroll
    for (int n = 0; n < 30; ++n) acc[n] = 0.f;
    const int base = lane * 48;
#pragma unroll 8
    for (int j = 0; j < 48; ++j) {
      const int idx = base + j;
      const float v = (idx < 1024) ? b_cls[idx]
                    : (idx < 2048) ? b_e1[idx - 1024] : b_e2[idx - 2048];
      const float* sj = Wd1o32 + (size_t)idx * LP;
#pragma unroll
      for (int n = 0; n < 30; ++n) acc[n] += v * sj[n];
    }
#pragma unroll
    for (int n = 0; n < 30; ++n) {
#pragma unroll
      for (int m = 1; m < 64; m <<= 1) acc[n] += __shfl_xor(acc[n], m);
    }
    if (lane == 0) {
#pragma unroll
      for (int n = 0; n < 30; ++n) rbias[n] = acc[n];
    }
  } else if (wid == 1) {
    fold_row<LP>(b_d1, P1p, rbias + LP);
  } else if (wid == 2) {
    fold_row<30>(b_d2, W_out, rbias + 2 * LP);
  }
}

// ---------------------------------------------------------------------------
// Final: T[b] in LDS (tanh(x0), tanh(span means from 32-row partials)), then
// out[b][n] = T[b] . Wfold32[:,n] + btot[n].  grid B, block 256.
// ---------------------------------------------------------------------------
__global__ __launch_bounds__(256) void final_kernel(
    const float* __restrict__ x, const int* __restrict__ eidx,
    const float* __restrict__ Pspan, const float* __restrict__ Wf,
    const float* __restrict__ b_out, const float* __restrict__ rbias,
    float* __restrict__ out) {
  __shared__ float Ts[3 * H_];
  __shared__ float red[8][30];
  const int b = blockIdx.x;
  const int t = threadIdx.x;
  const int col = t * 4;

  {
    float4 v = *(const float4*)(x + (size_t)b * S_ * H_ + col);
    Ts[col + 0] = tanhf(v.x);
    Ts[col + 1] = tanhf(v.y);
    Ts[col + 2] = tanhf(v.z);
    Ts[col + 3] = tanhf(v.w);
  }
#pragma unroll
  for (int role = 0; role < 2; ++role) {
    const int lo = eidx[b * 4 + 2 * role];
    const int hi = eidx[b * 4 + 2 * role + 1];
    const int c0 = lo >> 5;
    const int c1 = (hi - 1) >> 5;
    float ax = 0.f, ay = 0.f, az = 0.f, aw = 0.f;
    for (int c = c0; c <= c1; ++c) {
      float4 v = *(const float4*)(Pspan + (((size_t)b * 2 + role) * NCHUNK + c) * H_ + col);
      ax += v.x; ay += v.y; az += v.z; aw += v.w;
    }
    const float inv = 1.0f / (float)(hi - lo);
    float* Td = Ts + (1 + role) * H_ + col;
    Td[0] = tanhf(ax * inv);
    Td[1] = tanhf(ay * inv);
    Td[2] = tanhf(az * inv);
    Td[3] = tanhf(aw * inv);
  }
  __syncthreads();

  if (t < 240) {
    const int n = t % 30, p = t / 30;
    const int k0 = p * 384;
    float s = 0.f;
#pragma unroll 4
    for (int k = k0; k < k0 + 384; ++k) s += Ts[k] * Wf[(size_t)k * LP + n];
    red[p][n] = s;
  }
  __syncthreads();
  if (t < L_) {
    float s = b_out[t] + rbias[t] + rbias[LP + t] + rbias[2 * LP + t];
#pragma unroll
    for (int p = 0; p < 8; ++p) s += red[p][t];
    out[(size_t)b * L_ + t] = s;
  }
}

extern "C" void kernel_launch(void* const* d_in, const int* in_sizes, int n_in,
                              void* d_out, int out_size, void* d_ws, size_t ws_size,
                              hipStream_t stream) {
  const float* x = (const float*)d_in[0];
  const int* eidx = (const int*)d_in[1];
  const float* W_cls = (const float*)d_in[2];
  const float* b_cls = (const float*)d_in[3];
  const float* W_e1 = (const float*)d_in[4];
  const float* b_e1 = (const float*)d_in[5];
  const float* W_e2 = (const float*)d_in[6];
  const float* b_e2 = (const float*)d_in[7];
  const float* W_d1 = (const float*)d_in[8];
  const float* b_d1 = (const float*)d_in[9];
  const float* W_d2 = (const float*)d_in[10];
  const float* b_d2 = (const float*)d_in[11];
  const float* W_out = (const float*)d_in[12];
  const float* b_out = (const float*)d_in[13];
  float* out = (float*)d_out;

  float* ws = (float*)d_ws;
  float* Pspan   = ws;                 // 256*2*16*1024 = 8,388,608
  float* P1p     = Pspan + 8388608;    // 1024*32 = 32,768
  float* Wd1o32  = P1p + 32768;        // 3072*32 = 98,304
  float* Wfold32 = Wd1o32 + 98304;     // 3072*32 = 98,304
  float* rbias   = Wfold32 + 98304;    // 96
  // total ~8.6M floats ~34.5 MB

  // span partials + fold1 (P1 = W_d2 @ W_out) in one launch
  span_fold1_kernel<<<dim3(B_, NCHUNK + 1, 2), 256, 0, stream>>>(
      x, eidx, W_d2, W_out, Pspan, P1p);

  // Wd1o = W_d1 @ P1
  fold2_kernel<<<768, 256, 0, stream>>>(W_d1, P1p, Wd1o32);

  // Wfold[z] = W_z @ Wd1o[z]  + bias rows
  fold3_kernel<<<769, 256, 0, stream>>>(
      W_cls, W_e1, W_e2, Wd1o32, P1p, W_out,
      b_cls, b_e1, b_e2, b_d1, b_d2, Wfold32, rbias);

  final_kernel<<<B_, 256, 0, stream>>>(x, eidx, Pspan, Wfold32, b_out, rbias, out);
}